// Round 11
// baseline (270.485 us; speedup 1.0000x reference)
//
#include <hip/hip_runtime.h>
#include <math.h>

typedef _Float16 f16;
typedef _Float16 f16x8 __attribute__((ext_vector_type(8)));
typedef float f32x4 __attribute__((ext_vector_type(4)));

#define Bn 128
#define Tn 32
#define Hn 768
#define En 4
#define Fn 3072
#define Rn 256
#define MAXT4 67

static constexpr size_t OUT_ELEMS  = (size_t)Rn*Tn*Hn;
static constexpr size_t SCORES_OFF = OUT_ELEMS;
static constexpr size_t ROUTE_OFF  = OUT_ELEMS + Rn;
static constexpr size_t BIDX_OFF   = OUT_ELEMS + 2*Rn;
static constexpr size_t LOSS_OFF   = OUT_ELEMS + 3*Rn;

// ws byte offsets
#define WS_WSF    0u
#define WS_ROUTE  4096u
#define WS_GRP    8192u
#define WS_X16    16384u
#define WS_W1T    (WS_X16 + 2u*Bn*Tn*Hn)
#define WS_W2T    (WS_W1T + 2u*En*Hn*Fn)
#define WS_H1     (WS_W2T + 2u*En*Fn*Hn)

#define GLOAD16(g, l) __builtin_amdgcn_global_load_lds( \
    (const __attribute__((address_space(1))) unsigned int*)(g), \
    (__attribute__((address_space(3))) unsigned int*)(l), 16, 0, 0)

__device__ __forceinline__ float fast_gelu(float v) {
  float s = v * 0.70710678118f;
  float a = fabsf(s);
  float t = 1.0f / (1.0f + 0.3275911f * a);
  float y = t*(0.254829592f + t*(-0.284496736f + t*(1.421413741f +
            t*(-1.453152027f + t*1.061405429f))));
  float er = 1.0f - y * __expf(-a*a);
  er = (s < 0.0f) ? -er : er;
  return 0.5f * v * (1.0f + er);
}

// 4-wave gate: fused x->fp16 conversion + gating logits + softmax + top2.
__global__ __launch_bounds__(256) void gate_kernel(
    const float* __restrict__ x, const float* __restrict__ Wg,
    float* __restrict__ out, float* __restrict__ wsf, int* __restrict__ route,
    f16* __restrict__ x16)
{
  const int b = blockIdx.x;
  const int tid = threadIdx.x;
  const int w = tid >> 6, l = tid & 63;
  __shared__ float pacc[4][4];
  float a0=0.f, a1=0.f, a2=0.f, a3=0.f;
  const float* xb = x   + (size_t)b*Tn*Hn + (size_t)(w*8)*Hn;
  f16*         xh = x16 + (size_t)b*Tn*Hn + (size_t)(w*8)*Hn;
  #pragma unroll
  for (int k = 0; k < 12; ++k) {
    const int h = l + 64*k;
    const float w0 = Wg[0*Hn+h], w1 = Wg[1*Hn+h], w2 = Wg[2*Hn+h], w3 = Wg[3*Hn+h];
    #pragma unroll
    for (int t = 0; t < 8; ++t) {
      float v = xb[t*Hn + h];
      xh[t*Hn + h] = (f16)v;
      a0 += v*w0; a1 += v*w1; a2 += v*w2; a3 += v*w3;
    }
  }
  #pragma unroll
  for (int o = 32; o > 0; o >>= 1) {
    a0 += __shfl_down(a0,o); a1 += __shfl_down(a1,o);
    a2 += __shfl_down(a2,o); a3 += __shfl_down(a3,o);
  }
  if (l == 0) { pacc[w][0]=a0; pacc[w][1]=a1; pacc[w][2]=a2; pacc[w][3]=a3; }
  __syncthreads();
  if (tid == 0) {
    float lg[4];
    #pragma unroll
    for (int e = 0; e < 4; ++e)
      lg[e] = (pacc[0][e]+pacc[1][e]+pacc[2][e]+pacc[3][e]) * (1.0f/Tn);
    float m = fmaxf(fmaxf(lg[0],lg[1]), fmaxf(lg[2],lg[3]));
    float p[4]; float s = 0.f;
    #pragma unroll
    for (int e = 0; e < 4; ++e) { p[e] = expf(lg[e]-m); s += p[e]; }
    float inv = 1.f/s;
    #pragma unroll
    for (int e = 0; e < 4; ++e) { p[e] *= inv; wsf[b*4+e] = p[e]; }
    int i1 = 0;
    #pragma unroll
    for (int e = 1; e < 4; ++e) if (p[e] > p[i1]) i1 = e;
    int i2 = (i1 == 0) ? 1 : 0;
    #pragma unroll
    for (int e = 0; e < 4; ++e) if (e != i1 && p[e] > p[i2]) i2 = e;
    int idx[2] = {i1, i2};
    #pragma unroll
    for (int k = 0; k < 2; ++k) {
      int r = 2*b + k;
      float pv = p[idx[k]];
      wsf[512 + r] = pv;
      route[r] = idx[k];
      out[SCORES_OFF + r] = pv;
      out[ROUTE_OFF  + r] = (float)idx[k];
      out[BIDX_OFF   + r] = (float)r;
    }
  }
}

__global__ __launch_bounds__(64) void loss_kernel(
    const float* __restrict__ wsf, float* __restrict__ out)
{
  const int l = threadIdx.x;
  float i0=0.f,i1=0.f,i2=0.f,i3=0.f;
  for (int b = l; b < Bn; b += 64) {
    i0 += wsf[b*4+0]; i1 += wsf[b*4+1]; i2 += wsf[b*4+2]; i3 += wsf[b*4+3];
  }
  #pragma unroll
  for (int o = 32; o > 0; o >>= 1) {
    i0 += __shfl_down(i0,o); i1 += __shfl_down(i1,o);
    i2 += __shfl_down(i2,o); i3 += __shfl_down(i3,o);
  }
  if (l == 0) {
    float mean = 0.25f*(i0+i1+i2+i3);
    float d0=i0-mean, d1=i1-mean, d2=i2-mean, d3=i3-mean;
    float var = (d0*d0+d1*d1+d2*d2+d3*d3) * (1.f/3.f);
    out[LOSS_OFF] = var / (mean*mean);
  }
}

// grp: [0]=nt4; tiles at [8+3i]={e,bstart,nb<=4}; blist at [384..639]
__global__ __launch_bounds__(64) void group_kernel(
    const int* __restrict__ route, int* __restrict__ grp)
{
  const int l = threadIdx.x;
  int cnt = 0;
  if (l < 4) { for (int r = 0; r < Rn; ++r) cnt += (route[r] == l); }
  int c0 = __shfl(cnt, 0), c1 = __shfl(cnt, 1), c2 = __shfl(cnt, 2), c3 = __shfl(cnt, 3);
  int off = (l >= 1 ? c0 : 0) + (l >= 2 ? c1 : 0) + (l >= 3 ? c2 : 0);
  if (l < 4) {
    int p = off;
    for (int r = 0; r < Rn; ++r) if (route[r] == l) grp[384 + p++] = r;
  }
  if (l == 0) {
    int cs[4] = {c0, c1, c2, c3};
    int os[4] = {0, c0, c0+c1, c0+c1+c2};
    int nt4 = 0;
    for (int e = 0; e < 4; ++e) {
      for (int s = 0; s < cs[e]; s += 4) {
        int nb = cs[e] - s; if (nb > 4) nb = 4;
        grp[8+nt4*3+0] = e; grp[8+nt4*3+1] = os[e]+s; grp[8+nt4*3+2] = nb;
        ++nt4;
      }
    }
    grp[0] = nt4;
  }
}

// Merged transpose+convert for W1 and W2: flat grid of 64x64 tiles.
__global__ __launch_bounds__(256) void transcvt_kernel(
    const float* __restrict__ W1s, const float* __restrict__ W2s,
    f16* __restrict__ d1, f16* __restrict__ d2)
{
  __shared__ f16 t[64][74];
  int bid = blockIdx.x;
  const float* s; f16* d; int R, C, rc;
  if (bid < 2304) { s = W1s; d = d1; R = Hn; C = Fn; rc = bid; }
  else            { s = W2s; d = d2; R = Fn; C = Hn; rc = bid - 2304; }
  const int e = rc / 576; rc -= e*576;
  const int nx = C >> 6;
  const int cy = rc / nx, cx = rc - cy*nx;
  const int r0 = cy*64, c0 = cx*64;
  s += (size_t)e*R*C;
  d += (size_t)e*R*C;
  const int tid = threadIdx.x;
  const int i  = tid >> 2;
  const int j0 = (tid & 3) * 16;
  #pragma unroll
  for (int q = 0; q < 16; q += 4) {
    float4 v = *(const float4*)(s + (size_t)(r0+i)*C + c0 + j0 + q);
    t[i][j0+q+0]=(f16)v.x; t[i][j0+q+1]=(f16)v.y; t[i][j0+q+2]=(f16)v.z; t[i][j0+q+3]=(f16)v.w;
  }
  __syncthreads();
  f16 o[16];
  #pragma unroll
  for (int q = 0; q < 16; ++q) o[q] = t[j0+q][i];
  *(uint4*)(d + (size_t)(c0+i)*R + r0 + j0)     = *(uint4*)&o[0];
  *(uint4*)(d + (size_t)(c0+i)*R + r0 + j0 + 8) = *(uint4*)&o[8];
}

// ---------------------------------------------------------------------------
// Grouped GEMM, occupancy-first: 4 waves (256 thr), BM=128, BK=32, dbuf 32KB
// -> 4 blocks/CU co-resident.  Wave grid 2x2, wave-tile 64x(NI*16).
// One barrier per K-tile: [ds_read(k); STAGE(k+1); lgkm0; 16*NI/4 MFMA; vm0; bar]
// ny-major grid: consecutive blocks share the B panel.
// g1: BN=128 NI=4 (1608 jobs).  g2: BN=64 NI=2 (804 jobs).
// ---------------------------------------------------------------------------
template<int KD, int ND, int BN, int NI, bool G1>
__global__ __launch_bounds__(256, 4) void gemm_kernel(
    const f16* __restrict__ A16, const f16* __restrict__ B16,
    const float* __restrict__ bias, f16* __restrict__ oh,
    float* __restrict__ of, const int* __restrict__ grp,
    const float* __restrict__ wsf)
{
  constexpr int NT   = KD / 32;
  constexpr int GL_B = BN / 64;             // B 16B-units per thread (2 or 1)
  constexpr int BUFSZ = (128 + BN) * 64;
  static_assert(NT % 2 == 0, "NT even");

  const int ntiles = grp[0];
  const int ny  = blockIdx.x / MAXT4;
  const int tix = blockIdx.x % MAXT4;
  if (tix >= ntiles) return;
  const int e      = grp[8+tix*3+0];
  const int bstart = grp[8+tix*3+1];
  const int nb     = grp[8+tix*3+2];
  const int n0     = ny * BN;
  const int tid    = threadIdx.x;
  const int lane   = tid & 63;
  const int w      = tid >> 6;

  extern __shared__ __align__(16) char smem[];

  // ---- staging sources: LDS unit (row,u) holds global unit u^((row>>1)&3) ----
  const f16* asrc[2];
  #pragma unroll
  for (int i = 0; i < 2; ++i) {
    const int U   = w*128 + i*64 + lane;
    const int row = U >> 2;
    const int gu  = (U & 3) ^ ((U >> 3) & 3);
    int slot = row >> 5; if (slot >= nb) slot = nb - 1;
    const int beam = grp[384 + bstart + slot];
    const size_t rbase = (G1 ? (size_t)(beam>>1)*Tn : (size_t)beam*Tn) + (row & 31);
    asrc[i] = A16 + rbase*(size_t)KD + gu*8;
  }
  const f16* bsrc[GL_B];
  #pragma unroll
  for (int i = 0; i < GL_B; ++i) {
    const int U   = w*(GL_B*64) + i*64 + lane;
    const int row = U >> 2;
    const int gu  = (U & 3) ^ ((U >> 3) & 3);
    bsrc[i] = B16 + (size_t)e*ND*KD + (size_t)(n0 + row)*KD + gu*8;
  }

  // ---- fragment geometry: wave grid 2x2 ----
  const int wm = w >> 1, wn = w & 1;
  const int lr = lane & 15, lk = lane >> 4;
  const int rowA0 = wm*64;
  const int rowB0 = wn*(NI*16);
  const int ub = (lk ^ ((lr >> 1) & 3)) << 4;

  f32x4 acc[4][NI];
  #pragma unroll
  for (int i=0;i<4;++i)
    #pragma unroll
    for (int j=0;j<NI;++j) acc[i][j] = (f32x4){0.f,0.f,0.f,0.f};

  auto STAGE = [&](int bsel, int kt2) {
    char* Ad = smem + bsel*BUFSZ + (w*128)*16;
    #pragma unroll
    for (int i = 0; i < 2; ++i) GLOAD16(asrc[i] + kt2*32, Ad + i*1024);
    char* Bd = smem + bsel*BUFSZ + 8192 + (w*(GL_B*64))*16;
    #pragma unroll
    for (int i = 0; i < GL_B; ++i) GLOAD16(bsrc[i] + kt2*32, Bd + i*1024);
  };

  auto TILE = [&](int k, int b) {
    const char* Ab = smem + b*BUFSZ;
    const char* Bb = Ab + 8192;
    f16x8 af[4], bf[NI];
    #pragma unroll
    for (int mi=0;mi<4;++mi)
      af[mi] = *(const f16x8*)(Ab + (rowA0 + mi*16 + lr)*64 + ub);
    #pragma unroll
    for (int ni=0;ni<NI;++ni)
      bf[ni] = *(const f16x8*)(Bb + (rowB0 + ni*16 + lr)*64 + ub);
    if (k + 1 < NT) STAGE(b ^ 1, k + 1);
    asm volatile("s_waitcnt lgkmcnt(0)" ::: "memory");
    __builtin_amdgcn_sched_barrier(0);
    #pragma unroll
    for (int mi=0;mi<4;++mi)
      #pragma unroll
      for (int ni=0;ni<NI;++ni)
        acc[mi][ni] = __builtin_amdgcn_mfma_f32_16x16x32_f16(af[mi], bf[ni], acc[mi][ni], 0, 0, 0);
    asm volatile("s_waitcnt vmcnt(0)" ::: "memory");
    __builtin_amdgcn_sched_barrier(0);
    __builtin_amdgcn_s_barrier();
    __builtin_amdgcn_sched_barrier(0);
  };

  // prologue: stage tile 0, certify
  STAGE(0, 0);
  asm volatile("s_waitcnt vmcnt(0)" ::: "memory");
  __builtin_amdgcn_sched_barrier(0);
  __builtin_amdgcn_s_barrier();
  __builtin_amdgcn_sched_barrier(0);

  for (int k = 0; k < NT; k += 2) {
    TILE(k,   0);
    TILE(k+1, 1);
  }

  // ---- epilogue: two 64-row halves through 32KB swizzled LDS ----
  const int nvalid = nb * Tn;
  char* cst = smem;
  float bvals[NI];
  #pragma unroll
  for (int ni=0;ni<NI;++ni)
    if (G1) bvals[ni] = bias[e*ND + n0 + rowB0 + ni*16 + lr];

  #pragma unroll
  for (int h = 0; h < 2; ++h) {
    if (wm == h) {
      #pragma unroll
      for (int mi=0;mi<4;++mi){
        #pragma unroll
        for (int j=0;j<4;++j){
          const int m = mi*16 + (lane>>4)*4 + j;      // row within half
          const int m7 = m & 7;
          #pragma unroll
          for (int ni=0;ni<NI;++ni){
            const int n = rowB0 + ni*16 + lr;
            if (G1) {
              float v = acc[mi][ni][j] + bvals[ni];
              *(f16*)(cst + m*512 + (((n>>3)^m7)<<4) + (n&7)*2) = (f16)fast_gelu(v);
            } else {
              *(float*)(cst + m*512 + (((n>>2)^m7)<<4) + (n&3)*4) = acc[mi][ni][j];
            }
          }
        }
      }
    }
    __syncthreads();
    {
      const int u  = tid & 15;             // 16B unit within row (16 units)
      const int tr = tid >> 4;             // 16 rows per iteration
      float4 b4;
      if (!G1) b4 = *(const float4*)(bias + e*ND + n0 + u*4);
      #pragma unroll
      for (int it = 0; it < 4; ++it) {
        const int rl = it*16 + tr;         // row within half
        const int r  = h*64 + rl;          // row within tile
        if (r < nvalid) {
          const int beam = grp[384 + bstart + (r>>5)];
          const char* src = cst + rl*512 + ((u ^ (rl&7))<<4);
          if (G1) {
            uint4 v = *(const uint4*)src;
            *(uint4*)(oh + ((size_t)beam*Tn + (r&31))*(size_t)ND + n0 + u*8) = v;
          } else {
            const float sc = wsf[512 + beam];
            float4 v = *(const float4*)src;
            v.x = (v.x + b4.x)*sc; v.y = (v.y + b4.y)*sc;
            v.z = (v.z + b4.z)*sc; v.w = (v.w + b4.w)*sc;
            *(float4*)(of + ((size_t)beam*Tn + (r&31))*(size_t)Hn + n0 + u*4) = v;
          }
        }
      }
    }
    __syncthreads();
  }
}

extern "C" void kernel_launch(void* const* d_in, const int* in_sizes, int n_in,
                              void* d_out, int out_size, void* d_ws, size_t ws_size,
                              hipStream_t stream)
{
  const float* x  = (const float*)d_in[0];
  const float* Wg = (const float*)d_in[1];
  const float* W1 = (const float*)d_in[2];
  const float* b1 = (const float*)d_in[3];
  const float* W2 = (const float*)d_in[4];
  const float* b2 = (const float*)d_in[5];
  float* out = (float*)d_out;
  char* ws = (char*)d_ws;
  float* wsf  = (float*)(ws + WS_WSF);
  int*   route= (int*)(ws + WS_ROUTE);
  int*   grp  = (int*)(ws + WS_GRP);
  f16*   x16  = (f16*)(ws + WS_X16);
  f16*   w1t  = (f16*)(ws + WS_W1T);
  f16*   w2t  = (f16*)(ws + WS_W2T);
  f16*   h1   = (f16*)(ws + WS_H1);

  gate_kernel<<<Bn, 256, 0, stream>>>(x, Wg, out, wsf, route, x16);
  group_kernel<<<1, 64, 0, stream>>>(route, grp);
  loss_kernel<<<1, 64, 0, stream>>>(wsf, out);
  transcvt_kernel<<<4608, 256, 0, stream>>>(W1, W2, w1t, w2t);

  auto g1 = gemm_kernel<Hn, Fn, 128, 4, true>;    // 256 thr, 32KB -> 4 blk/CU
  auto g2 = gemm_kernel<Fn, Hn,  64, 2, false>;   // 256 thr, 32KB -> 4 blk/CU
  const int smB = 32768;
  hipFuncSetAttribute((const void*)g1, hipFuncAttributeMaxDynamicSharedMemorySize, smB);
  hipFuncSetAttribute((const void*)g2, hipFuncAttributeMaxDynamicSharedMemorySize, smB);
  g1<<<24*MAXT4, 256, smB, stream>>>(x16, w1t, b1, h1, nullptr, grp, wsf);
  g2<<<12*MAXT4, 256, smB, stream>>>(h1, w2t, b2, nullptr, out, grp, wsf);
}

// Round 13
// 212.016 us; speedup vs baseline: 1.2758x; 1.2758x over previous
//
#include <hip/hip_runtime.h>
#include <math.h>

typedef _Float16 f16;
typedef _Float16 f16x8 __attribute__((ext_vector_type(8)));
typedef float f32x4 __attribute__((ext_vector_type(4)));

#define Bn 128
#define Tn 32
#define Hn 768
#define En 4
#define Fn 3072
#define Rn 256
#define MAXT8 35
#define MAXT4 67

static constexpr size_t OUT_ELEMS  = (size_t)Rn*Tn*Hn;
static constexpr size_t SCORES_OFF = OUT_ELEMS;
static constexpr size_t ROUTE_OFF  = OUT_ELEMS + Rn;
static constexpr size_t BIDX_OFF   = OUT_ELEMS + 2*Rn;
static constexpr size_t LOSS_OFF   = OUT_ELEMS + 3*Rn;

#define WS_WSF    0u
#define WS_ROUTE  4096u
#define WS_GRP    8192u
#define WS_X16    16384u
#define WS_W1T    (WS_X16 + 2u*Bn*Tn*Hn)
#define WS_W2T    (WS_W1T + 2u*En*Hn*Fn)
#define WS_H1     (WS_W2T + 2u*En*Fn*Hn)

#define GLOAD16(g, l) __builtin_amdgcn_global_load_lds( \
    (const __attribute__((address_space(1))) unsigned int*)(g), \
    (__attribute__((address_space(3))) unsigned int*)(l), 16, 0, 0)

#define SBAR()  __builtin_amdgcn_s_barrier()
#define SCHED() __builtin_amdgcn_sched_barrier(0)

__device__ __forceinline__ float fast_gelu(float v) {
  float s = v * 0.70710678118f;
  float a = fabsf(s);
  float t = 1.0f / (1.0f + 0.3275911f * a);
  float y = t*(0.254829592f + t*(-0.284496736f + t*(1.421413741f +
            t*(-1.453152027f + t*1.061405429f))));
  float er = 1.0f - y * __expf(-a*a);
  er = (s < 0.0f) ? -er : er;
  return 0.5f * v * (1.0f + er);
}

__global__ __launch_bounds__(256) void gate_kernel(
    const float* __restrict__ x, const float* __restrict__ Wg,
    float* __restrict__ out, float* __restrict__ wsf, int* __restrict__ route,
    f16* __restrict__ x16)
{
  const int b = blockIdx.x;
  const int tid = threadIdx.x;
  const int w = tid >> 6, l = tid & 63;
  __shared__ float pacc[4][4];
  float a0=0.f, a1=0.f, a2=0.f, a3=0.f;
  const float* xb = x   + (size_t)b*Tn*Hn + (size_t)(w*8)*Hn;
  f16*         xh = x16 + (size_t)b*Tn*Hn + (size_t)(w*8)*Hn;
  #pragma unroll
  for (int k = 0; k < 12; ++k) {
    const int h = l + 64*k;
    const float w0 = Wg[0*Hn+h], w1 = Wg[1*Hn+h], w2 = Wg[2*Hn+h], w3 = Wg[3*Hn+h];
    #pragma unroll
    for (int t = 0; t < 8; ++t) {
      float v = xb[t*Hn + h];
      xh[t*Hn + h] = (f16)v;
      a0 += v*w0; a1 += v*w1; a2 += v*w2; a3 += v*w3;
    }
  }
  #pragma unroll
  for (int o = 32; o > 0; o >>= 1) {
    a0 += __shfl_down(a0,o); a1 += __shfl_down(a1,o);
    a2 += __shfl_down(a2,o); a3 += __shfl_down(a3,o);
  }
  if (l == 0) { pacc[w][0]=a0; pacc[w][1]=a1; pacc[w][2]=a2; pacc[w][3]=a3; }
  __syncthreads();
  if (tid == 0) {
    float lg[4];
    #pragma unroll
    for (int e = 0; e < 4; ++e)
      lg[e] = (pacc[0][e]+pacc[1][e]+pacc[2][e]+pacc[3][e]) * (1.0f/Tn);
    float m = fmaxf(fmaxf(lg[0],lg[1]), fmaxf(lg[2],lg[3]));
    float p[4]; float s = 0.f;
    #pragma unroll
    for (int e = 0; e < 4; ++e) { p[e] = expf(lg[e]-m); s += p[e]; }
    float inv = 1.f/s;
    #pragma unroll
    for (int e = 0; e < 4; ++e) { p[e] *= inv; wsf[b*4+e] = p[e]; }
    int i1 = 0;
    #pragma unroll
    for (int e = 1; e < 4; ++e) if (p[e] > p[i1]) i1 = e;
    int i2 = (i1 == 0) ? 1 : 0;
    #pragma unroll
    for (int e = 0; e < 4; ++e) if (e != i1 && p[e] > p[i2]) i2 = e;
    int idx[2] = {i1, i2};
    #pragma unroll
    for (int k = 0; k < 2; ++k) {
      int r = 2*b + k;
      float pv = p[idx[k]];
      wsf[512 + r] = pv;
      route[r] = idx[k];
      out[SCORES_OFF + r] = pv;
      out[ROUTE_OFF  + r] = (float)idx[k];
      out[BIDX_OFF   + r] = (float)r;
    }
  }
}

__global__ __launch_bounds__(64) void loss_kernel(
    const float* __restrict__ wsf, float* __restrict__ out)
{
  const int l = threadIdx.x;
  float i0=0.f,i1=0.f,i2=0.f,i3=0.f;
  for (int b = l; b < Bn; b += 64) {
    i0 += wsf[b*4+0]; i1 += wsf[b*4+1]; i2 += wsf[b*4+2]; i3 += wsf[b*4+3];
  }
  #pragma unroll
  for (int o = 32; o > 0; o >>= 1) {
    i0 += __shfl_down(i0,o); i1 += __shfl_down(i1,o);
    i2 += __shfl_down(i2,o); i3 += __shfl_down(i3,o);
  }
  if (l == 0) {
    float mean = 0.25f*(i0+i1+i2+i3);
    float d0=i0-mean, d1=i1-mean, d2=i2-mean, d3=i3-mean;
    float var = (d0*d0+d1*d1+d2*d2+d3*d3) * (1.f/3.f);
    out[LOSS_OFF] = var / (mean*mean);
  }
}

// grp: [0]=nt8, [1]=nt4; tiles8 at [8+3i] (nb<=8); tiles4 at [128+3i] (nb<=4);
// blist at [384..639]
__global__ __launch_bounds__(64) void group_kernel(
    const int* __restrict__ route, int* __restrict__ grp)
{
  const int l = threadIdx.x;
  int cnt = 0;
  if (l < 4) { for (int r = 0; r < Rn; ++r) cnt += (route[r] == l); }
  int c0 = __shfl(cnt, 0), c1 = __shfl(cnt, 1), c2 = __shfl(cnt, 2), c3 = __shfl(cnt, 3);
  int off = (l >= 1 ? c0 : 0) + (l >= 2 ? c1 : 0) + (l >= 3 ? c2 : 0);
  if (l < 4) {
    int p = off;
    for (int r = 0; r < Rn; ++r) if (route[r] == l) grp[384 + p++] = r;
  }
  if (l == 0) {
    int cs[4] = {c0, c1, c2, c3};
    int os[4] = {0, c0, c0+c1, c0+c1+c2};
    int nt8 = 0, nt4 = 0;
    for (int e = 0; e < 4; ++e) {
      for (int s = 0; s < cs[e]; s += 8) {
        int nb = cs[e] - s; if (nb > 8) nb = 8;
        grp[8+nt8*3+0] = e; grp[8+nt8*3+1] = os[e]+s; grp[8+nt8*3+2] = nb;
        ++nt8;
      }
      for (int s = 0; s < cs[e]; s += 4) {
        int nb = cs[e] - s; if (nb > 4) nb = 4;
        grp[128+nt4*3+0] = e; grp[128+nt4*3+1] = os[e]+s; grp[128+nt4*3+2] = nb;
        ++nt4;
      }
    }
    grp[0] = nt8;
    grp[1] = nt4;
  }
}

__global__ __launch_bounds__(256) void transcvt_kernel(
    const float* __restrict__ W1s, const float* __restrict__ W2s,
    f16* __restrict__ d1, f16* __restrict__ d2)
{
  __shared__ f16 t[64][74];
  int bid = blockIdx.x;
  const float* s; f16* d; int R, C, rc;
  if (bid < 2304) { s = W1s; d = d1; R = Hn; C = Fn; rc = bid; }
  else            { s = W2s; d = d2; R = Fn; C = Hn; rc = bid - 2304; }
  const int e = rc / 576; rc -= e*576;
  const int nx = C >> 6;
  const int cy = rc / nx, cx = rc - cy*nx;
  const int r0 = cy*64, c0 = cx*64;
  s += (size_t)e*R*C;
  d += (size_t)e*R*C;
  const int tid = threadIdx.x;
  const int i  = tid >> 2;
  const int j0 = (tid & 3) * 16;
  #pragma unroll
  for (int q = 0; q < 16; q += 4) {
    float4 v = *(const float4*)(s + (size_t)(r0+i)*C + c0 + j0 + q);
    t[i][j0+q+0]=(f16)v.x; t[i][j0+q+1]=(f16)v.y; t[i][j0+q+2]=(f16)v.z; t[i][j0+q+3]=(f16)v.w;
  }
  __syncthreads();
  f16 o[16];
  #pragma unroll
  for (int q = 0; q < 16; ++q) o[q] = t[j0+q][i];
  *(uint4*)(d + (size_t)(c0+i)*R + r0 + j0)     = *(uint4*)&o[0];
  *(uint4*)(d + (size_t)(c0+i)*R + r0 + j0 + 8) = *(uint4*)&o[8];
}

// ---------------------------------------------------------------------------
// g1: m201-style 8-phase GEMM.  BM=BN=256, BK=64, 8 waves (2x4), wave-tile
// 128x64.  LDS 128KB: 2 bufs x {A-half0,A-half1,B-half0,B-half1} x 16KB.
// STAGE uses WAVE-UNIFORM lds dst (m104/m108): base = d*65536 + region +
// h*16384 + w*2048, two gloads at +0,+1024; lane lands at base+lane*16.
// Phases per K-tile: p0(0,0) 12 ds_reads; p1(0,1) 4; p2(1,0) 8 + stage B(kt+2);
// p3(1,1) stage A(kt+2).  Tile end: vmcnt(8).
// ---------------------------------------------------------------------------
__global__ __launch_bounds__(512) void gemm1_kernel(
    const f16* __restrict__ A16, const f16* __restrict__ B16,
    const float* __restrict__ bias, f16* __restrict__ oh,
    const int* __restrict__ grp)
{
  constexpr int KD = Hn, ND = Fn, NT = KD/64, NY = Fn/256;
  const int ntiles = grp[0];
  const int tix = blockIdx.x / NY;
  const int ny  = blockIdx.x % NY;
  if (tix >= ntiles) return;
  const int e      = grp[8+tix*3+0];
  const int bstart = grp[8+tix*3+1];
  const int nb     = grp[8+tix*3+2];
  const int n0     = ny * 256;
  const int tid    = threadIdx.x;
  const int lane   = tid & 63;
  const int w      = tid >> 6;

  extern __shared__ __align__(16) char smem[];

  // staging sources, per (h, i): linear LDS unit U = w*128 + i*64 + lane;
  // LDS unit U holds global unit (U&7)^((U>>3)&7) of row U>>3 (pre-swizzle).
  const f16* aS[2][2];
  const f16* bS[2][2];
  #pragma unroll
  for (int h = 0; h < 2; ++h) {
    #pragma unroll
    for (int i = 0; i < 2; ++i) {
      const int U = w*128 + i*64 + lane;
      const int r128 = U >> 3;
      const int gu = (U & 7) ^ (r128 & 7);
      const int rowA = h*128 + r128;
      int slot = rowA >> 5; if (slot >= nb) slot = nb - 1;
      const int beam = grp[384 + bstart + slot];
      aS[h][i] = A16 + ((size_t)(beam>>1)*Tn + (rowA&31))*(size_t)KD + gu*8;
      bS[h][i] = B16 + (size_t)e*ND*KD + (size_t)(n0 + h*128 + r128)*KD + gu*8;
    }
  }

  // fragment geometry: wave (wm 0..1, wn 0..3); wave-tile 128x64
  const int wm = w >> 2, wn = w & 3;
  const int lr = lane & 15, lk = lane >> 4;
  const int r7 = lr & 7;
  const char* Abase = smem + wm*16384;                 // + d*65536
  const char* Bbase = smem + 32768 + (wn>>1)*16384;    // + d*65536
  const int cb = (wn & 1) * 64;

  f32x4 acc[8][4];
  #pragma unroll
  for (int i=0;i<8;++i)
    #pragma unroll
    for (int j=0;j<4;++j) acc[i][j] = (f32x4){0.f,0.f,0.f,0.f};

  auto STAGE_A = [&](int d, int h, int kt) {
    char* dst = smem + d*65536 + h*16384 + w*2048;      // wave-uniform base
    GLOAD16(aS[h][0] + kt*64, dst);
    GLOAD16(aS[h][1] + kt*64, dst + 1024);
  };
  auto STAGE_B = [&](int d, int h, int kt) {
    char* dst = smem + d*65536 + 32768 + h*16384 + w*2048;
    GLOAD16(bS[h][0] + kt*64, dst);
    GLOAD16(bS[h][1] + kt*64, dst + 1024);
  };

  f16x8 af[4][2], bf[2][2][2];

#define LDA(MH, MI, KS) \
  *(const f16x8*)(Abase + d*65536 + ((MH)*64 + (MI)*16 + lr)*128 + (((KS)*4+lk)^r7)*16)
#define LDB(NH, NI, KS) \
  *(const f16x8*)(Bbase + d*65536 + (cb + (NH)*32 + (NI)*16 + lr)*128 + (((KS)*4+lk)^r7)*16)
#define MFMA16(MH, NH) \
  __builtin_amdgcn_s_setprio(1); \
  _Pragma("unroll") \
  for (int mi=0;mi<4;++mi) \
    _Pragma("unroll") \
    for (int ni=0;ni<2;++ni) \
      _Pragma("unroll") \
      for (int ks=0;ks<2;++ks) \
        acc[(MH)*4+mi][(NH)*2+ni] = __builtin_amdgcn_mfma_f32_16x16x32_f16( \
            af[mi][ks], bf[NH][ni][ks], acc[(MH)*4+mi][(NH)*2+ni], 0, 0, 0); \
  __builtin_amdgcn_s_setprio(0);

  // prologue: stage K-tiles 0,1; certify tile 0
  STAGE_A(0,0,0); STAGE_A(0,1,0); STAGE_B(0,0,0); STAGE_B(0,1,0);
  STAGE_A(1,0,1); STAGE_A(1,1,1); STAGE_B(1,0,1); STAGE_B(1,1,1);
  asm volatile("s_waitcnt vmcnt(8)" ::: "memory");
  SCHED(); SBAR(); SCHED();

  for (int kt = 0; kt < NT; ++kt) {
    const int d = kt & 1;
    const bool st = (kt + 2 < NT);
    // p0 (mh0, nh0): 12 ds_reads
    #pragma unroll
    for (int mi=0;mi<4;++mi) { af[mi][0] = LDA(0,mi,0); af[mi][1] = LDA(0,mi,1); }
    #pragma unroll
    for (int ni=0;ni<2;++ni) { bf[0][ni][0] = LDB(0,ni,0); bf[0][ni][1] = LDB(0,ni,1); }
    SBAR(); SCHED();
    asm volatile("s_waitcnt lgkmcnt(0)" ::: "memory");
    SCHED();
    MFMA16(0,0);
    SBAR(); SCHED();
    // p1 (mh0, nh1): 4 ds_reads
    #pragma unroll
    for (int ni=0;ni<2;++ni) { bf[1][ni][0] = LDB(1,ni,0); bf[1][ni][1] = LDB(1,ni,1); }
    SBAR(); SCHED();
    asm volatile("s_waitcnt lgkmcnt(0)" ::: "memory");
    SCHED();
    MFMA16(0,1);
    SBAR(); SCHED();
    // p2 (mh1, nh0): 8 ds_reads + stage B(kt+2) (B region dead after p1 barrier)
    #pragma unroll
    for (int mi=0;mi<4;++mi) { af[mi][0] = LDA(1,mi,0); af[mi][1] = LDA(1,mi,1); }
    if (st) { STAGE_B(d, 0, kt+2); STAGE_B(d, 1, kt+2); }
    SBAR(); SCHED();
    asm volatile("s_waitcnt lgkmcnt(0)" ::: "memory");
    SCHED();
    MFMA16(1,0);
    SBAR(); SCHED();
    // p3 (mh1, nh1): stage A(kt+2) (A region dead after p2 barrier)
    if (st) { STAGE_A(d, 0, kt+2); STAGE_A(d, 1, kt+2); }
    SBAR(); SCHED();
    MFMA16(1,1);
    if (st)                asm volatile("s_waitcnt vmcnt(8)" ::: "memory");
    else if (kt + 1 < NT)  asm volatile("s_waitcnt vmcnt(0)" ::: "memory");
    SCHED(); SBAR(); SCHED();
  }
#undef LDA
#undef LDB
#undef MFMA16

  // ---- epilogue: 256 rows through swizzled LDS (128 KB) ----
  __syncthreads();
  const int nvalid = nb * Tn;
  char* cst = smem;
  float bvals[4];
  #pragma unroll
  for (int ni=0;ni<4;++ni) bvals[ni] = bias[e*ND + n0 + wn*64 + ni*16 + lr];

  #pragma unroll
  for (int mi=0;mi<8;++mi){
    #pragma unroll
    for (int j=0;j<4;++j){
      const int m = wm*128 + mi*16 + (lane>>4)*4 + j;
      const int m7 = m & 7;
      #pragma unroll
      for (int ni=0;ni<4;++ni){
        const int n = wn*64 + ni*16 + lr;
        float v = acc[mi][ni][j] + bvals[ni];
        *(f16*)(cst + m*512 + (((n>>3)^m7)<<4) + (n&7)*2) = (f16)fast_gelu(v);
      }
    }
  }
  __syncthreads();
  {
    const int u  = tid & 31;
    const int tr = tid >> 5;
    #pragma unroll
    for (int it = 0; it < 16; ++it) {
      const int r = it*16 + tr;
      if (r < nvalid) {
        const int beam = grp[384 + bstart + (r>>5)];
        uint4 v = *(const uint4*)(cst + r*512 + (((u&24)|((u&7)^(r&7)))<<4));
        *(uint4*)(oh + ((size_t)beam*Tn + (r&31))*(size_t)ND + n0 + u*8) = v;
      }
    }
  }
}

// ---------------------------------------------------------------------------
// g2: R10's proven kernel (triple-buffer BK=32, counted vmcnt, 4 waves).
// ---------------------------------------------------------------------------
template<int KD, int ND, int BN, int NWAVE>
__global__ __launch_bounds__(NWAVE*64, 2) void gemm2_kernel(
    const f16* __restrict__ A16, const f16* __restrict__ B16,
    const float* __restrict__ bias, float* __restrict__ of,
    const int* __restrict__ grp, const float* __restrict__ wsf)
{
  constexpr int NWY  = BN / 64;
  constexpr int NY   = ND / BN;
  constexpr int NT   = KD / 32;
  constexpr int NTHR = NWAVE * 64;
  constexpr int GL_A = 512 / NTHR;
  constexpr int GL_B = (BN*4) / NTHR;
  constexpr int NLD  = GL_A + GL_B;
  constexpr int BUFSZ = 8192 + BN*64;
  constexpr int TPR  = NWAVE * 2;
  static_assert(NT % 3 == 0, "NT%3");

  const int ntiles = grp[1];
  const int tix = blockIdx.x / NY;
  const int ny  = blockIdx.x % NY;
  if (tix >= ntiles) return;
  const int e      = grp[128+tix*3+0];
  const int bstart = grp[128+tix*3+1];
  const int nb     = grp[128+tix*3+2];
  const int n0     = ny * BN;
  const int tid    = threadIdx.x;
  const int lane   = tid & 63;
  const int w      = tid >> 6;

  extern __shared__ __align__(16) char smem[];

  const f16* asrc[GL_A];
  #pragma unroll
  for (int i = 0; i < GL_A; ++i) {
    const int U   = w*(GL_A*64) + i*64 + lane;
    const int row = U >> 2;
    const int gu  = (U & 3) ^ ((U >> 3) & 3);
    int slot = row >> 5; if (slot >= nb) slot = nb - 1;
    const int beam = grp[384 + bstart + slot];
    const size_t rbase = (size_t)beam*Tn + (row & 31);
    asrc[i] = A16 + rbase*(size_t)KD + gu*8;
  }
  const f16* bsrc[GL_B];
  #pragma unroll
  for (int i = 0; i < GL_B; ++i) {
    const int U   = w*(GL_B*64) + i*64 + lane;
    const int row = U >> 2;
    const int gu  = (U & 3) ^ ((U >> 3) & 3);
    bsrc[i] = B16 + (size_t)e*ND*KD + (size_t)(n0 + row)*KD + gu*8;
  }

  const int wm = w / NWY, wn = w % NWY;
  const int lr = lane & 15, lk = lane >> 4;
  const int rowA0 = wm*64;
  const int rowB0 = wn*64;
  const int ub = (lk ^ ((lr >> 1) & 3)) << 4;

  f32x4 acc[4][4];
  #pragma unroll
  for (int i=0;i<4;++i)
    #pragma unroll
    for (int j=0;j<4;++j) acc[i][j] = (f32x4){0.f,0.f,0.f,0.f};

  auto STAGE = [&](int bsel, int kt2) {
    char* Ad = smem + bsel*BUFSZ + (w*(GL_A*64))*16;
    #pragma unroll
    for (int i = 0; i < GL_A; ++i) GLOAD16(asrc[i] + kt2*32, Ad + i*1024);
    char* Bd = smem + bsel*BUFSZ + 8192 + (w*(GL_B*64))*16;
    #pragma unroll
    for (int i = 0; i < GL_B; ++i) GLOAD16(bsrc[i] + kt2*32, Bd + i*1024);
  };

  auto TILE = [&](int k, int b, bool dost, int vmc) {
    const char* Ab = smem + b*BUFSZ;
    const char* Bb = Ab + 8192;
    f16x8 af[4], bf[4];
    #pragma unroll
    for (int mi=0;mi<4;++mi)
      af[mi] = *(const f16x8*)(Ab + (rowA0 + mi*16 + lr)*64 + ub);
    #pragma unroll
    for (int ni=0;ni<4;++ni)
      bf[ni] = *(const f16x8*)(Bb + (rowB0 + ni*16 + lr)*64 + ub);
    if (dost) STAGE((b+2)%3, k+2);
    SCHED(); SBAR(); SCHED();
    asm volatile("s_waitcnt lgkmcnt(0)" ::: "memory");
    SCHED();
    __builtin_amdgcn_s_setprio(1);
    #pragma unroll
    for (int mi=0;mi<4;++mi)
      #pragma unroll
      for (int ni=0;ni<4;++ni)
        acc[mi][ni] = __builtin_amdgcn_mfma_f32_16x16x32_f16(af[mi], bf[ni], acc[mi][ni], 0, 0, 0);
    __builtin_amdgcn_s_setprio(0);
    if (vmc > 0)       asm volatile("s_waitcnt vmcnt(%0)" :: "i"(NLD) : "memory");
    else if (vmc == 0) asm volatile("s_waitcnt vmcnt(0)" ::: "memory");
    SCHED(); SBAR(); SCHED();
  };

  STAGE(0, 0);
  STAGE(1, 1);
  asm volatile("s_waitcnt vmcnt(%0)" :: "i"(NLD) : "memory");
  SCHED(); SBAR(); SCHED();

  {
    int b = 0;
    for (int k = 0; k < NT-2; ++k) {
      TILE(k, b, true, NLD);
      b = (b+1)%3;
    }
    TILE(NT-2, b, false, 0);
    b = (b+1)%3;
    TILE(NT-1, b, false, -1);
  }

  const int nvalid = nb * Tn;
  char* cst = smem;
  #pragma unroll
  for (int mi=0;mi<4;++mi){
    #pragma unroll
    for (int j=0;j<4;++j){
      const int m = rowA0 + mi*16 + (lane>>4)*4 + j;
      const int m7 = m & 7;
      #pragma unroll
      for (int ni=0;ni<4;++ni){
        const int n = rowB0 + ni*16 + lr;
        *(float*)(cst + m*512 + (((n>>2)^m7)<<4) + (n&3)*4) = acc[mi][ni][j];
      }
    }
  }
  __syncthreads();
  {
    const int u  = tid & 31;
    const int tr = tid >> 5;
    float4 b4 = *(const float4*)(bias + e*ND + n0 + u*4);
    #pragma unroll
    for (int it = 0; it < 128/TPR; ++it) {
      const int rl = it*TPR + tr;
      if (rl < nvalid) {
        const int beam = grp[384 + bstart + (rl>>5)];
        const float sc = wsf[512 + beam];
        float4 v = *(const float4*)(cst + rl*512 + (((u&24)|((u&7)^(rl&7)))<<4));
        v.x = (v.x + b4.x)*sc; v.y = (v.y + b4.y)*sc;
        v.z = (v.z + b4.z)*sc; v.w = (v.w + b4.w)*sc;
        *(float4*)(of + ((size_t)beam*Tn + (rl&31))*(size_t)Hn + n0 + u*4) = v;
      }
    }
  }
}

extern "C" void kernel_launch(void* const* d_in, const int* in_sizes, int n_in,
                              void* d_out, int out_size, void* d_ws, size_t ws_size,
                              hipStream_t stream)
{
  const float* x  = (const float*)d_in[0];
  const float* Wg = (const float*)d_in[1];
  const float* W1 = (const float*)d_in[2];
  const float* b1 = (const float*)d_in[3];
  const float* W2 = (const float*)d_in[4];
  const float* b2 = (const float*)d_in[5];
  float* out = (float*)d_out;
  char* ws = (char*)d_ws;
  float* wsf  = (float*)(ws + WS_WSF);
  int*   route= (int*)(ws + WS_ROUTE);
  int*   grp  = (int*)(ws + WS_GRP);
  f16*   x16  = (f16*)(ws + WS_X16);
  f16*   w1t  = (f16*)(ws + WS_W1T);
  f16*   w2t  = (f16*)(ws + WS_W2T);
  f16*   h1   = (f16*)(ws + WS_H1);

  gate_kernel<<<Bn, 256, 0, stream>>>(x, Wg, out, wsf, route, x16);
  group_kernel<<<1, 64, 0, stream>>>(route, grp);
  loss_kernel<<<1, 64, 0, stream>>>(wsf, out);
  transcvt_kernel<<<4608, 256, 0, stream>>>(W1, W2, w1t, w2t);

  auto g2 = gemm2_kernel<Fn, Hn, 128, 4>;
  const int sm1 = 131072;
  const int sm2 = 65536;
  hipFuncSetAttribute((const void*)gemm1_kernel, hipFuncAttributeMaxDynamicSharedMemorySize, sm1);
  hipFuncSetAttribute((const void*)g2, hipFuncAttributeMaxDynamicSharedMemorySize, sm2);
  gemm1_kernel<<<MAXT8*12, 512, sm1, stream>>>(x16, w1t, b1, h1, grp);
  g2<<<MAXT4*6, 256, sm2, stream>>>(h1, w2t, b2, out, grp, wsf);
}